// Round 9
// baseline (144.363 us; speedup 1.0000x reference)
//
#include <hip/hip_runtime.h>

typedef __attribute__((ext_vector_type(8))) short bf16x8;
typedef __attribute__((ext_vector_type(4))) float floatx4;

__device__ __forceinline__ unsigned short f2bf(float f) {
    unsigned int u = __float_as_uint(f);
    u += 0x7FFFu + ((u >> 16) & 1u);
    return (unsigned short)(u >> 16);
}

// ---- prep: [0,1024) x->NHWC bf16 | [1024,1312) Wk frag-major | [1312,1384) Woff frag-major ----
// Fragment-major: elem (tap, tile=mt*2+kc, lane, j) at flat [tap*T + tile*512 + lane*8 + j],
// holding W[row = mt*16 + (lane&15)][k = kc*32 + (lane>>4)*8 + j] for that tap.
__global__ __launch_bounds__(256) void prep_all(const float* __restrict__ x,
        const float* __restrict__ Wk, const float* __restrict__ Woff,
        unsigned short* __restrict__ xt, unsigned short* __restrict__ Wkb2,
        unsigned short* __restrict__ Woffb) {
    int bb = blockIdx.x;
    if (bb < 1024) {
        __shared__ float tile[64][65];
        int b = bb >> 6, y = bb & 63;
        const float* src = x + (size_t)b * 262144 + y * 64;   // + c*4096 + xc
        int tx = threadIdx.x & 15, tg = threadIdx.x >> 4;
#pragma unroll
        for (int i = 0; i < 4; i++) {
            int c = tg + i * 16;
            float4 v = *(const float4*)(src + (size_t)c * 4096 + tx * 4);
            tile[c][tx * 4 + 0] = v.x; tile[c][tx * 4 + 1] = v.y;
            tile[c][tx * 4 + 2] = v.z; tile[c][tx * 4 + 3] = v.w;
        }
        __syncthreads();
        unsigned short* dst = xt + (size_t)bb * 4096;   // [xc][c] bf16
#pragma unroll
        for (int i = 0; i < 4; i++) {
            int xc = tg + i * 16;
            int c4 = tx * 4;
            ushort4 v;
            v.x = f2bf(tile[c4 + 0][xc]); v.y = f2bf(tile[c4 + 1][xc]);
            v.z = f2bf(tile[c4 + 2][xc]); v.w = f2bf(tile[c4 + 3][xc]);
            *(ushort4*)(dst + xc * 64 + c4) = v;
        }
    } else if (bb < 1312) {
        int idx = (bb - 1024) * 256 + threadIdx.x;      // [0, 73728): 9 taps x 16 tiles x 512
        int tap = idx >> 13;
        int r = idx & 8191;
        int tile = r >> 9;
        int ln = (r >> 3) & 63;
        int j = r & 7;
        int mt = tile >> 1, kc = tile & 1;
        int oc = mt * 16 + (ln & 15);
        int c = kc * 32 + (ln >> 4) * 8 + j;
        Wkb2[idx] = f2bf(Wk[(oc * 64 + c) * 9 + tap]);
    } else {
        int idx = (bb - 1312) * 256 + threadIdx.x;      // [0, 18432): 9 taps x 4 tiles x 512
        int tap = idx >> 11;
        int r = idx & 2047;
        int tile = r >> 9;
        int ln = (r >> 3) & 63;
        int j = r & 7;
        int mt = tile >> 1, kc = tile & 1;
        int n = mt * 16 + (ln & 15);
        int c = kc * 32 + (ln >> 4) * 8 + j;
        float v = (n < 18) ? Woff[(n * 64 + c) * 9 + tap] : 0.f;
        Woffb[idx] = f2bf(v);
    }
}

// ---- fused kernel, barrier-free K-loops: A-frags loaded straight from global
//      (frag-major, L1/L2-resident), B-frags register-direct gathers. LDS only
//      holds the 18 offset channels per pixel (5 KB) -> high free-running occupancy. ----
__global__ __launch_bounds__(256, 4) void fused_kernel(
        const unsigned short* __restrict__ xt,     // [b][y][x][c] bf16
        const unsigned short* __restrict__ Wkb2,   // frag-major, 9*8192
        const unsigned short* __restrict__ Woffb,  // frag-major, 9*2048
        const float* __restrict__ boff,
        const float* __restrict__ bias,
        float* __restrict__ out) {
    __shared__ float offs[64][20];                 // 5.1 KB
    int tid = threadIdx.x;
    int wave = tid >> 6, lane = tid & 63;
    int frow = lane & 15, quad = lane >> 4;
    // XCD-aware remap: 2 whole batch images per XCD
    int bb = blockIdx.x;
    int xcd = bb & 7, idx = bb >> 3;
    int b = xcd * 2 + (idx >> 6);
    int pxBase = (idx & 63) * 64;
    int pl = wave * 16 + frow;                     // block-local pixel
    int px = pxBase + pl;
    int y = px >> 6, xx = px & 63;
    const char* img = (const char*)(xt + (size_t)b * 262144) + quad * 16;
    const unsigned short* wofL = Woffb + lane * 8;
    const unsigned short* wkL  = Wkb2 + lane * 8;

    // ================= GEMM1: offset conv (no barriers) =================
    floatx4 acc1[2];
    acc1[0] = (floatx4)(0.f); acc1[1] = (floatx4)(0.f);
    for (int tap = 0; tap < 9; tap++) {
        int ry = y + tap / 3 - 1, rx = xx + tap % 3 - 1;
        bool valid = (ry >= 0) & (ry < 64) & (rx >= 0) & (rx < 64);
        const char* src = img + ((ry * 64 + rx) << 7);
        bf16x8 bz = {};
        const unsigned short* wt = wofL + tap * 2048;
#pragma unroll
        for (int kc = 0; kc < 2; kc++) {
            bf16x8 bfr = valid ? *(const bf16x8*)(src + kc * 64) : bz;
#pragma unroll
            for (int mt = 0; mt < 2; mt++) {
                bf16x8 af = *(const bf16x8*)(wt + (mt * 2 + kc) * 512);
                acc1[mt] = __builtin_amdgcn_mfma_f32_16x16x32_bf16(af, bfr, acc1[mt], 0, 0, 0);
            }
        }
    }
    // D: col=frow(px), row=quad*4+rg (+mt*16) -> offset channel n of pixel pl
#pragma unroll
    for (int mt = 0; mt < 2; mt++)
#pragma unroll
        for (int rg = 0; rg < 4; rg++) {
            int n = mt * 16 + quad * 4 + rg;
            if (n < 18) offs[pl][n] = acc1[mt][rg] + boff[n];
        }
    __syncthreads();                               // offs visible (same-wave lanes, kept for safety)

    // ================= GEMM2: bilinear sample + main conv (no barriers) =================
    floatx4 acc[8];
#pragma unroll
    for (int i = 0; i < 8; i++) acc[i] = (floatx4)(0.f);

    for (int tap = 0; tap < 9; tap++) {
        float orow = offs[pl][tap];
        float ocol = offs[pl][9 + tap];
        float pr = (float)(y + tap / 3 - 1) + orow;
        float pc = (float)(xx + tap % 3 - 1) + ocol;
        pr = fminf(fmaxf(pr, 0.f), 63.f);
        pc = fminf(fmaxf(pc, 0.f), 63.f);
        float fr = floorf(pr), fc = floorf(pc);
        float tr = pr - fr, tc = pc - fc;
        int r0 = (int)fr, c0 = (int)fc;
        int r1 = min(r0 + 1, 63), c1 = min(c0 + 1, 63);
        float w00 = (1.f - tr) * (1.f - tc);
        float w01 = (1.f - tr) * tc;
        float w10 = tr * (1.f - tc);
        float w11 = tr * tc;
        int o00 = (r0 * 64 + c0) * 128;
        int o01 = (r0 * 64 + c1) * 128;
        int o10 = (r1 * 64 + c0) * 128;
        int o11 = (r1 * 64 + c1) * 128;
        const unsigned short* wt = wkL + tap * 8192;

#pragma unroll
        for (int kc = 0; kc < 2; kc++) {
            int4 u00 = __builtin_bit_cast(int4, *(const bf16x8*)(img + o00 + kc * 64));
            int4 u01 = __builtin_bit_cast(int4, *(const bf16x8*)(img + o01 + kc * 64));
            int4 u10 = __builtin_bit_cast(int4, *(const bf16x8*)(img + o10 + kc * 64));
            int4 u11 = __builtin_bit_cast(int4, *(const bf16x8*)(img + o11 + kc * 64));
            int4 r;
#pragma unroll
            for (int wd = 0; wd < 4; wd++) {
                int a00 = (wd == 0) ? u00.x : (wd == 1) ? u00.y : (wd == 2) ? u00.z : u00.w;
                int a01 = (wd == 0) ? u01.x : (wd == 1) ? u01.y : (wd == 2) ? u01.z : u01.w;
                int a10 = (wd == 0) ? u10.x : (wd == 1) ? u10.y : (wd == 2) ? u10.z : u10.w;
                int a11 = (wd == 0) ? u11.x : (wd == 1) ? u11.y : (wd == 2) ? u11.z : u11.w;
                float vl = w00 * __uint_as_float((unsigned)a00 << 16)
                         + w01 * __uint_as_float((unsigned)a01 << 16)
                         + w10 * __uint_as_float((unsigned)a10 << 16)
                         + w11 * __uint_as_float((unsigned)a11 << 16);
                float vh = w00 * __uint_as_float((unsigned)a00 & 0xffff0000u)
                         + w01 * __uint_as_float((unsigned)a01 & 0xffff0000u)
                         + w10 * __uint_as_float((unsigned)a10 & 0xffff0000u)
                         + w11 * __uint_as_float((unsigned)a11 & 0xffff0000u);
                unsigned pk = __builtin_amdgcn_perm(
                    __float_as_uint(vh) + 0x8000u,
                    __float_as_uint(vl) + 0x8000u, 0x07060302u);
                if (wd == 0) r.x = (int)pk; else if (wd == 1) r.y = (int)pk;
                else if (wd == 2) r.z = (int)pk; else r.w = (int)pk;
            }
            bf16x8 bfrag = __builtin_bit_cast(bf16x8, r);
#pragma unroll
            for (int mt = 0; mt < 8; mt++) {
                bf16x8 af = *(const bf16x8*)(wt + (mt * 2 + kc) * 512);
                acc[mt] = __builtin_amdgcn_mfma_f32_16x16x32_bf16(af, bfrag, acc[mt], 0, 0, 0);
            }
        }
    }

    // --- epilogue: D col=frow (px), row=quad*4+rg (oc) ---
    float* outb = out + (size_t)b * 524288 + px;
#pragma unroll
    for (int mt = 0; mt < 8; mt++) {
#pragma unroll
        for (int rg = 0; rg < 4; rg++) {
            int oc = mt * 16 + quad * 4 + rg;
            outb[oc * 4096] = acc[mt][rg] + bias[oc];
        }
    }
}

extern "C" void kernel_launch(void* const* d_in, const int* in_sizes, int n_in,
                              void* d_out, int out_size, void* d_ws, size_t ws_size,
                              hipStream_t stream) {
    const float* x    = (const float*)d_in[0];
    const float* Woff = (const float*)d_in[1];
    const float* boff = (const float*)d_in[2];
    const float* Wk   = (const float*)d_in[3];
    const float* bk   = (const float*)d_in[4];
    float* out = (float*)d_out;

    char* ws = (char*)d_ws;
    unsigned short* xt    = (unsigned short*)ws;               // 8388608 B
    unsigned short* Wkb2  = (unsigned short*)(ws + 8388608);   // 147456 B
    unsigned short* Woffb = (unsigned short*)(ws + 8536064);   // 36864 B

    prep_all<<<1384, 256, 0, stream>>>(x, Wk, Woff, xt, Wkb2, Woffb);
    fused_kernel<<<1024, 256, 0, stream>>>(xt, Wkb2, Woffb, boff, bk, out);
}

// Round 10
// 133.178 us; speedup vs baseline: 1.0840x; 1.0840x over previous
//
#include <hip/hip_runtime.h>

typedef __attribute__((ext_vector_type(8))) short bf16x8;
typedef __attribute__((ext_vector_type(4))) float floatx4;

__device__ __forceinline__ unsigned short f2bf(float f) {
    unsigned int u = __float_as_uint(f);
    u += 0x7FFFu + ((u >> 16) & 1u);
    return (unsigned short)(u >> 16);
}

// ---- prep: [0,1024) x->NHWC bf16 | [1024,1312) Wk frag-major | [1312,1384) Woff frag-major ----
__global__ __launch_bounds__(256) void prep_all(const float* __restrict__ x,
        const float* __restrict__ Wk, const float* __restrict__ Woff,
        unsigned short* __restrict__ xt, unsigned short* __restrict__ Wkb2,
        unsigned short* __restrict__ Woffb) {
    int bb = blockIdx.x;
    if (bb < 1024) {
        __shared__ float tile[64][65];
        int b = bb >> 6, y = bb & 63;
        const float* src = x + (size_t)b * 262144 + y * 64;   // + c*4096 + xc
        int tx = threadIdx.x & 15, tg = threadIdx.x >> 4;
#pragma unroll
        for (int i = 0; i < 4; i++) {
            int c = tg + i * 16;
            float4 v = *(const float4*)(src + (size_t)c * 4096 + tx * 4);
            tile[c][tx * 4 + 0] = v.x; tile[c][tx * 4 + 1] = v.y;
            tile[c][tx * 4 + 2] = v.z; tile[c][tx * 4 + 3] = v.w;
        }
        __syncthreads();
        unsigned short* dst = xt + (size_t)bb * 4096;   // [xc][c] bf16
#pragma unroll
        for (int i = 0; i < 4; i++) {
            int xc = tg + i * 16;
            int c4 = tx * 4;
            ushort4 v;
            v.x = f2bf(tile[c4 + 0][xc]); v.y = f2bf(tile[c4 + 1][xc]);
            v.z = f2bf(tile[c4 + 2][xc]); v.w = f2bf(tile[c4 + 3][xc]);
            *(ushort4*)(dst + xc * 64 + c4) = v;
        }
    } else if (bb < 1312) {
        int idx = (bb - 1024) * 256 + threadIdx.x;      // 9 taps x 16 tiles x 512
        int tap = idx >> 13;
        int r = idx & 8191;
        int tile = r >> 9;
        int ln = (r >> 3) & 63;
        int j = r & 7;
        int mt = tile >> 1, kc = tile & 1;
        int oc = mt * 16 + (ln & 15);
        int c = kc * 32 + (ln >> 4) * 8 + j;
        Wkb2[idx] = f2bf(Wk[(oc * 64 + c) * 9 + tap]);
    } else {
        int idx = (bb - 1312) * 256 + threadIdx.x;      // 9 taps x 4 tiles x 512
        int tap = idx >> 11;
        int r = idx & 2047;
        int tile = r >> 9;
        int ln = (r >> 3) & 63;
        int j = r & 7;
        int mt = tile >> 1, kc = tile & 1;
        int n = mt * 16 + (ln & 15);
        int c = kc * 32 + (ln >> 4) * 8 + j;
        float v = (n < 18) ? Woff[(n * 64 + c) * 9 + tap] : 0.f;
        Woffb[idx] = f2bf(v);
    }
}

__device__ __forceinline__ bf16x8 blend4(int4 u00, int4 u01, int4 u10, int4 u11,
        float w00, float w01, float w10, float w11) {
    int4 r;
#pragma unroll
    for (int wd = 0; wd < 4; wd++) {
        int a00 = (wd == 0) ? u00.x : (wd == 1) ? u00.y : (wd == 2) ? u00.z : u00.w;
        int a01 = (wd == 0) ? u01.x : (wd == 1) ? u01.y : (wd == 2) ? u01.z : u01.w;
        int a10 = (wd == 0) ? u10.x : (wd == 1) ? u10.y : (wd == 2) ? u10.z : u10.w;
        int a11 = (wd == 0) ? u11.x : (wd == 1) ? u11.y : (wd == 2) ? u11.z : u11.w;
        float vl = w00 * __uint_as_float((unsigned)a00 << 16)
                 + w01 * __uint_as_float((unsigned)a01 << 16)
                 + w10 * __uint_as_float((unsigned)a10 << 16)
                 + w11 * __uint_as_float((unsigned)a11 << 16);
        float vh = w00 * __uint_as_float((unsigned)a00 & 0xffff0000u)
                 + w01 * __uint_as_float((unsigned)a01 & 0xffff0000u)
                 + w10 * __uint_as_float((unsigned)a10 & 0xffff0000u)
                 + w11 * __uint_as_float((unsigned)a11 & 0xffff0000u);
        unsigned pk = __builtin_amdgcn_perm(
            __float_as_uint(vh) + 0x8000u,
            __float_as_uint(vl) + 0x8000u, 0x07060302u);
        if (wd == 0) r.x = (int)pk; else if (wd == 1) r.y = (int)pk;
        else if (wd == 2) r.z = (int)pk; else r.w = (int)pk;
    }
    return __builtin_bit_cast(bf16x8, r);
}

// ---- fused kernel: GEMM1 (offset conv, barrier-free, A from L1) ->
//      GEMM2 (bilinear+conv, A dbuf in LDS, B-gathers software-pipelined 1 tap ahead) ----
__global__ __launch_bounds__(256, 4) void fused_kernel(
        const unsigned short* __restrict__ xt,     // [b][y][x][c] bf16
        const unsigned short* __restrict__ Wkb2,   // frag-major, 9*8192
        const unsigned short* __restrict__ Woffb,  // frag-major, 9*2048
        const float* __restrict__ boff,
        const float* __restrict__ bias,
        float* __restrict__ out) {
    __shared__ unsigned short As[2][8192];         // 32 KB
    __shared__ float offs[64][20];                 // 5.1 KB
    int tid = threadIdx.x;
    int wave = tid >> 6, lane = tid & 63;
    int frow = lane & 15, quad = lane >> 4;
    int bb = blockIdx.x;
    int xcd = bb & 7, idx = bb >> 3;
    int b = xcd * 2 + (idx >> 6);
    int pxBase = (idx & 63) * 64;
    int pl = wave * 16 + frow;
    int px = pxBase + pl;
    int y = px >> 6, xx = px & 63;
    const char* img = (const char*)(xt + (size_t)b * 262144) + quad * 16;
    const unsigned short* wofL = Woffb + lane * 8;

    // ================= GEMM1: offset conv (barrier-free) =================
    floatx4 acc1[2];
    acc1[0] = (floatx4)(0.f); acc1[1] = (floatx4)(0.f);
#pragma unroll
    for (int tap = 0; tap < 9; tap++) {
        int ry = y + tap / 3 - 1, rx = xx + tap % 3 - 1;
        bool valid = (ry >= 0) & (ry < 64) & (rx >= 0) & (rx < 64);
        const char* src = img + ((ry * 64 + rx) << 7);
        bf16x8 bz = {};
        const unsigned short* wt = wofL + tap * 2048;
#pragma unroll
        for (int kc = 0; kc < 2; kc++) {
            bf16x8 bfr = valid ? *(const bf16x8*)(src + kc * 64) : bz;
#pragma unroll
            for (int mt = 0; mt < 2; mt++) {
                bf16x8 af = *(const bf16x8*)(wt + (mt * 2 + kc) * 512);
                acc1[mt] = __builtin_amdgcn_mfma_f32_16x16x32_bf16(af, bfr, acc1[mt], 0, 0, 0);
            }
        }
    }
#pragma unroll
    for (int mt = 0; mt < 2; mt++)
#pragma unroll
        for (int rg = 0; rg < 4; rg++) {
            int n = mt * 16 + quad * 4 + rg;
            if (n < 18) offs[pl][n] = acc1[mt][rg] + boff[n];
        }
    __syncthreads();

    // ================= GEMM2: pipelined =================
    floatx4 acc[8];
#pragma unroll
    for (int i = 0; i < 8; i++) acc[i] = (floatx4)(0.f);

    // prologue: As[0] <- A(0); aw <- A(1); issue corners(0)
    bf16x8 aw[4];
#pragma unroll
    for (int i = 0; i < 4; i++)
        aw[i] = *(const bf16x8*)(Wkb2 + i * 2048 + tid * 8);
#pragma unroll
    for (int i = 0; i < 4; i++)
        *(bf16x8*)&As[0][i * 2048 + tid * 8] = aw[i];
#pragma unroll
    for (int i = 0; i < 4; i++)
        aw[i] = *(const bf16x8*)(Wkb2 + 8192 + i * 2048 + tid * 8);

    int4 c[8];                // in-flight corners: [corner*2 + kc]
    float w00, w01, w10, w11; // weights matching c
    {
        float orow = offs[pl][0], ocol = offs[pl][9];
        float pr = (float)(y - 1) + orow;
        float pc = (float)(xx - 1) + ocol;
        pr = fminf(fmaxf(pr, 0.f), 63.f);
        pc = fminf(fmaxf(pc, 0.f), 63.f);
        float fr = floorf(pr), fc = floorf(pc);
        float tr = pr - fr, tc = pc - fc;
        int r0 = (int)fr, c0 = (int)fc;
        int r1 = min(r0 + 1, 63), c1 = min(c0 + 1, 63);
        w00 = (1.f - tr) * (1.f - tc); w01 = (1.f - tr) * tc;
        w10 = tr * (1.f - tc);         w11 = tr * tc;
        int o00 = (r0 * 64 + c0) * 128, o01 = (r0 * 64 + c1) * 128;
        int o10 = (r1 * 64 + c0) * 128, o11 = (r1 * 64 + c1) * 128;
#pragma unroll
        for (int kc = 0; kc < 2; kc++) {
            c[0 + kc] = *(const int4*)(img + o00 + kc * 64);
            c[2 + kc] = *(const int4*)(img + o01 + kc * 64);
            c[4 + kc] = *(const int4*)(img + o10 + kc * 64);
            c[6 + kc] = *(const int4*)(img + o11 + kc * 64);
        }
    }

#pragma unroll
    for (int tap = 0; tap < 9; tap++) {
        __syncthreads();                        // As[tap&1] ready
        // blend corners issued last iter (latency already hidden)
        bf16x8 bfrag[2];
#pragma unroll
        for (int kc = 0; kc < 2; kc++)
            bfrag[kc] = blend4(c[0 + kc], c[2 + kc], c[4 + kc], c[6 + kc],
                               w00, w01, w10, w11);
        // issue next tap's corners (regs now free)
        if (tap < 8) {
            int nt = tap + 1;
            float orow = offs[pl][nt], ocol = offs[pl][9 + nt];
            float pr = (float)(y + nt / 3 - 1) + orow;
            float pc = (float)(xx + nt % 3 - 1) + ocol;
            pr = fminf(fmaxf(pr, 0.f), 63.f);
            pc = fminf(fmaxf(pc, 0.f), 63.f);
            float fr = floorf(pr), fc = floorf(pc);
            float tr = pr - fr, tc = pc - fc;
            int r0 = (int)fr, c0 = (int)fc;
            int r1 = min(r0 + 1, 63), c1 = min(c0 + 1, 63);
            w00 = (1.f - tr) * (1.f - tc); w01 = (1.f - tr) * tc;
            w10 = tr * (1.f - tc);         w11 = tr * tc;
            int o00 = (r0 * 64 + c0) * 128, o01 = (r0 * 64 + c1) * 128;
            int o10 = (r1 * 64 + c0) * 128, o11 = (r1 * 64 + c1) * 128;
#pragma unroll
            for (int kc = 0; kc < 2; kc++) {
                c[0 + kc] = *(const int4*)(img + o00 + kc * 64);
                c[2 + kc] = *(const int4*)(img + o01 + kc * 64);
                c[4 + kc] = *(const int4*)(img + o10 + kc * 64);
                c[6 + kc] = *(const int4*)(img + o11 + kc * 64);
            }
        }
        // MFMA on current tap (A from LDS, conflict-free frag-major)
        const unsigned short* abuf = &As[tap & 1][0];
#pragma unroll
        for (int kc = 0; kc < 2; kc++)
#pragma unroll
            for (int mt = 0; mt < 8; mt++) {
                bf16x8 af = *(const bf16x8*)&abuf[(mt * 2 + kc) * 512 + lane * 8];
                acc[mt] = __builtin_amdgcn_mfma_f32_16x16x32_bf16(af, bfrag[kc], acc[mt], 0, 0, 0);
            }
        // stage A(tap+1) into the other buffer; prefetch A(tap+2)
        if (tap < 8) {
#pragma unroll
            for (int i = 0; i < 4; i++)
                *(bf16x8*)&As[(tap + 1) & 1][i * 2048 + tid * 8] = aw[i];
            if (tap < 7)
#pragma unroll
                for (int i = 0; i < 4; i++)
                    aw[i] = *(const bf16x8*)(Wkb2 + (tap + 2) * 8192 + i * 2048 + tid * 8);
        }
    }

    // --- epilogue: D col=frow (px), row=quad*4+rg (oc) ---
    float* outb = out + (size_t)b * 524288 + px;
#pragma unroll
    for (int mt = 0; mt < 8; mt++) {
#pragma unroll
        for (int rg = 0; rg < 4; rg++) {
            int oc = mt * 16 + quad * 4 + rg;
            outb[oc * 4096] = acc[mt][rg] + bias[oc];
        }
    }
}

extern "C" void kernel_launch(void* const* d_in, const int* in_sizes, int n_in,
                              void* d_out, int out_size, void* d_ws, size_t ws_size,
                              hipStream_t stream) {
    const float* x    = (const float*)d_in[0];
    const float* Woff = (const float*)d_in[1];
    const float* boff = (const float*)d_in[2];
    const float* Wk   = (const float*)d_in[3];
    const float* bk   = (const float*)d_in[4];
    float* out = (float*)d_out;

    char* ws = (char*)d_ws;
    unsigned short* xt    = (unsigned short*)ws;               // 8388608 B
    unsigned short* Wkb2  = (unsigned short*)(ws + 8388608);   // 147456 B
    unsigned short* Woffb = (unsigned short*)(ws + 8536064);   // 36864 B

    prep_all<<<1384, 256, 0, stream>>>(x, Wk, Woff, xt, Wkb2, Woffb);
    fused_kernel<<<1024, 256, 0, stream>>>(xt, Wkb2, Woffb, boff, bk, out);
}